// Round 12
// baseline (567.414 us; speedup 1.0000x reference)
//
#include <hip/hip_runtime.h>
#include <math.h>

// Problem constants
#define Bsz  4096
#define Tlen 512
#define NE   30
#define NIN  5
#define HD10 10
#define B10  (Bsz*HD10)   // per-head plane: 40960 floats

typedef _Float16 h2v  __attribute__((ext_vector_type(2)));
typedef _Float16 f16x8 __attribute__((ext_vector_type(8)));
typedef float    f32x4 __attribute__((ext_vector_type(4)));

__device__ __forceinline__ float fexp2(float x){ return __builtin_amdgcn_exp2f(x); }
__device__ __forceinline__ float frcp (float x){ return __builtin_amdgcn_rcpf(x); }
#define L2E 1.4426950408889634f

__device__ __forceinline__ void loadarr32(float arr[32], const float* bufrow){
  const float4* p4 = (const float4*)bufrow;
  #pragma unroll
  for (int q4=0;q4<8;q4++){ float4 vv=p4[q4]; arr[4*q4]=vv.x; arr[4*q4+1]=vv.y; arr[4*q4+2]=vv.z; arr[4*q4+3]=vv.w; }
}

// ---------------------------------------------------------------------------
// Kernel 1 (R12: single-wave MFMA LSTM): fused x-proj + recurrence + qkv.
// One WAVE (64 thr) per 16-batch group; grid 256 blocks x 64 thr.
// R8 diagnosis: 1247 cyc/step = ~325 issue + ~900 stall from the 2-wave
// dim-split (h exchanged via LDS + 2 barriers/step, 1 block/CU -> nothing
// hides the stall). R12: each wave owns ALL 30 dims via two 16-row A-frag
// halves per gate (16 MFMAs/step, same chip-total). The B-frag h-exchange
// becomes INTRA-WAVE: 8 __shfl + 4 selects. Zero LDS in the step loop,
// zero barriers, wave fully self-paced.
// Layouts (m89/m120-verified): A[m=lane&15][k=(lane>>4)*8+j],
//   B[k=(lane>>4)*8+j][n=lane&15], D[m=(lane>>4)*4+r][n=lane&15].
// Shuffle map: lane(q,n) needs dims 8q..8q+7 = frag f=q>>1, r=0..3 of
//   src quads 2q&3 and (2q+1)&3 -> sa=((q&1)<<5)+n, sb=sa+16.
// ---------------------------------------------------------------------------
extern "C" __global__ void __launch_bounds__(64)
lstm_k(const float* __restrict__ input, const float* __restrict__ w_ih,
       const float* __restrict__ w_hh, const float* __restrict__ b_ih,
       const float* __restrict__ b_hh, const float* __restrict__ in_proj_w,
       const float* __restrict__ in_proj_b,
       float* __restrict__ qo, float* __restrict__ ko, float* __restrict__ vo,
       float* __restrict__ ho)
{
  __shared__ __align__(16) float xstf[16*390];   // x: [n][t][6pad]
  const int lane = threadIdx.x & 63;
  const int n    = lane & 15;        // batch within group (B/D col; A row m)
  const int q    = lane >> 4;
  const int b0   = blockIdx.x * 16;

  // ---- A-frags + bias C-init (once), activation scale folded in ----
  f16x8 ah[2][4], ax[2][4];
  f32x4 bi[2][4];
  #pragma unroll
  for (int f=0; f<2; ++f){
    const int dimA  = 16*f + n;            // A row m = n
    const bool vA   = (dimA < NE);
    #pragma unroll
    for (int G=0; G<4; ++G){
      const float sG = (G==2) ? (-2.f*L2E) : (-L2E);
      const int grow = vA ? (NE*G + dimA) : 0;
      #pragma unroll
      for (int j=0;j<8;++j){
        const int k = 8*q + j;
        ah[f][G][j] = (vA && k < NE) ? (_Float16)(sG*w_hh[grow*NE + k]) : (_Float16)0;
        ax[f][G][j] = (vA && q==0 && j < NIN) ? (_Float16)(sG*w_ih[grow*NIN + j]) : (_Float16)0;
      }
      #pragma unroll
      for (int r=0;r<4;++r){
        const int d = 16*f + 4*q + r;      // D row m
        const int gr = (d < NE) ? (NE*G + d) : 0;
        bi[f][G][r] = (d < NE) ? sG*(b_ih[gr] + b_hh[gr]) : 0.f;
      }
    }
  }

  float cst[2][4];
  #pragma unroll
  for (int f=0;f<2;++f)
    #pragma unroll
    for (int r=0;r<4;++r) cst[f][r] = 0.f;
  // h packs: hp[f][0]=h2(r0,r1), hp[f][1]=h2(r2,r3) as dword bitcasts; 0 = fp16 0
  float hp[2][2] = {{0.f,0.f},{0.f,0.f}};
  float hf32[2][4];
  #pragma unroll
  for (int f=0;f<2;++f)
    #pragma unroll
    for (int r=0;r<4;++r) hf32[f][r] = 0.f;

  const int sa = ((q & 1) << 5) + n;
  const int sb = sa + 16;
  const bool q0 = (q == 0);
  const bool flo = (q < 2);
  const f16x8 zf8 = (f16x8)(_Float16)0;
  const float2* x2p = (const float2*)xstf;
  const int xb2 = n*195;

  for (int tc = 0; tc < Tlen; tc += 64) {
    __builtin_amdgcn_wave_barrier();
    for (int i = lane; i < 5120; i += 64){
      const int nn = i/320, e = i%320;
      xstf[nn*390 + (e/5)*6 + (e%5)] =
        input[(size_t)(b0+nn)*(Tlen*NIN) + tc*5 + e];
    }
    __builtin_amdgcn_wave_barrier();
    #pragma unroll 1
    for (int tl = 0; tl < 64; ++tl) {
      // x B-frag (quad0 lanes carry [x0..x4,0,0,0])
      const int bx2 = xb2 + tl*3;
      const float2 xa = x2p[bx2], xb = x2p[bx2+1], xc = x2p[bx2+2];
      union { f16x8 v; h2v h[4]; } U;
      U.h[0].x=(_Float16)xa.x; U.h[0].y=(_Float16)xa.y;
      U.h[1].x=(_Float16)xb.x; U.h[1].y=(_Float16)xb.y;
      U.h[2].x=(_Float16)xc.x; U.h[2].y=(_Float16)0;
      U.h[3]=(h2v)0;
      const f16x8 bx = q0 ? U.v : zf8;
      // h B-frag via intra-wave shuffles (8 shfl + 4 selects)
      const float t00 = __shfl(hp[0][0], sa, 64);
      const float t01 = __shfl(hp[0][1], sa, 64);
      const float t10 = __shfl(hp[1][0], sa, 64);
      const float t11 = __shfl(hp[1][1], sa, 64);
      const float u00 = __shfl(hp[0][0], sb, 64);
      const float u01 = __shfl(hp[0][1], sb, 64);
      const float u10 = __shfl(hp[1][0], sb, 64);
      const float u11 = __shfl(hp[1][1], sb, 64);
      union { f16x8 v; float d[4]; } BH;
      BH.d[0] = flo ? t00 : t10;
      BH.d[1] = flo ? t01 : t11;
      BH.d[2] = flo ? u00 : u10;
      BH.d[3] = flo ? u01 : u11;
      const f16x8 bh = BH.v;
      // 16 MFMAs: 2 dim-halves x 4 gates, x-phase then h-phase
      f32x4 C[2][4];
      #pragma unroll
      for (int f=0; f<2; ++f)
        #pragma unroll
        for (int G=0; G<4; ++G)
          C[f][G] = __builtin_amdgcn_mfma_f32_16x16x32_f16(ax[f][G], bx, bi[f][G], 0,0,0);
      #pragma unroll
      for (int f=0; f<2; ++f)
        #pragma unroll
        for (int G=0; G<4; ++G)
          C[f][G] = __builtin_amdgcn_mfma_f32_16x16x32_f16(ah[f][G], bh, C[f][G], 0,0,0);
      // activations (8 (f,r) states/lane); pre-scaled preacts:
      // sig = rcp(1+exp2(C)); g: tanh = 2*rcp(1+exp2(C)) - 1
      #pragma unroll
      for (int f=0; f<2; ++f){
        #pragma unroll
        for (int r=0; r<4; ++r){
          const float iv = frcp(1.f + fexp2(C[f][0][r]));
          const float fv = frcp(1.f + fexp2(C[f][1][r]));
          const float gv = fmaf(2.f, frcp(1.f + fexp2(C[f][2][r])), -1.f);
          const float ov = frcp(1.f + fexp2(C[f][3][r]));
          const float cn = fmaf(fv, cst[f][r], iv*gv);
          cst[f][r] = cn;
          const float r2 = frcp(1.f + fexp2((2.f*L2E)*cn));
          hf32[f][r] = ov * fmaf(-2.f, r2, 1.f);
        }
        h2v p01, p23;
        p01.x = (_Float16)hf32[f][0]; p01.y = (_Float16)hf32[f][1];
        p23.x = (_Float16)hf32[f][2]; p23.y = (_Float16)hf32[f][3];
        hp[f][0] = __builtin_bit_cast(float, p01);
        hp[f][1] = __builtin_bit_cast(float, p23);
      }
    }
  }

  // ---- tail: stash fp32 h,c (dims 16f+4q+r contiguous per f) ----
  float* hfb = xstf;            // [16][36]
  float* cfb = xstf + 16*36;
  __builtin_amdgcn_wave_barrier();
  #pragma unroll
  for (int f=0; f<2; ++f){
    float4 hv4; hv4.x=hf32[f][0]; hv4.y=hf32[f][1]; hv4.z=hf32[f][2]; hv4.w=hf32[f][3];
    float4 cv4; cv4.x=cst[f][0];  cv4.y=cst[f][1];  cv4.z=cst[f][2];  cv4.w=cst[f][3];
    *(float4*)(&hfb[n*36 + 16*f + 4*q]) = hv4;
    *(float4*)(&cfb[n*36 + 16*f + 4*q]) = cv4;
  }
  __builtin_amdgcn_wave_barrier();
  for (int i = lane; i < 16*NE; i += 64){
    const int nn = i/NE, d = i%NE;
    ho[(size_t)(b0+nn)*NE + d] = hfb[nn*36 + d];
  }
  const float QS = 0.31622776601683794f;     // 1/sqrt(10)
  for (int i = lane; i < 90*16; i += 64){
    const int o  = i % 90;
    const int nn = i / 90;
    const float* wrow = in_proj_w + o*NE;
    const float* src  = (o < NE) ? &hfb[nn*36] : &cfb[nn*36];
    float acc = in_proj_b[o];
    #pragma unroll
    for (int k2=0;k2<NE;k2++) acc = fmaf(wrow[k2], src[k2], acc);
    const int b = b0 + nn;
    if (o < 30)      { qo[(o/10)*B10 + b*10 + (o%10)] = acc * QS; }
    else if (o < 60) { const int u=o-30; ko[(u/10)*B10 + b*10 + (u%10)] = acc; }
    else             { const int u=o-60; vo[(u/10)*B10 + b*10 + (u%10)] = acc; }
  }
}

// ---------------------------------------------------------------------------
// Kernel 2: flash attention partials (R10-exact revert, best-known total).
// Thread = query. grid (16 qblocks, 3 heads, NS), block 256.
// 64-key K/V tiles staged cooperatively; compute reads LDS broadcasts.
// With lstm now fast, this kernel should SURFACE IN TOP-5 next profile,
// finally revealing the stubborn ~140us gap's true owner + counters.
// ---------------------------------------------------------------------------
extern "C" __global__ void __launch_bounds__(256)
attn_part(const float* __restrict__ q, const float* __restrict__ k,
          const float* __restrict__ v, float* __restrict__ part, int nkeys)
{
  __shared__ __align__(16) float kst[640];   // 64 keys x 10
  __shared__ __align__(16) float vst[640];
  const int t    = threadIdx.x;
  const int qr   = blockIdx.x*256 + t;
  const int head = blockIdx.y;
  const int ks   = blockIdx.z;
  const float* kh = k + (size_t)head*B10;
  const float* vh = v + (size_t)head*B10;
  float qreg[10];
  {
    const float2* qp = (const float2*)(q + (size_t)head*B10 + (size_t)qr*10);
    #pragma unroll
    for (int i=0;i<5;i++){ float2 t2=qp[i]; qreg[2*i]=t2.x; qreg[2*i+1]=t2.y; }
  }
  float m = -INFINITY, l = 0.f, acc[10];
  #pragma unroll
  for (int d=0;d<10;d++) acc[d]=0.f;

  const int k0 = ks * nkeys;
  const int nt = nkeys >> 6;           // 64-key tiles
  #pragma unroll 1
  for (int ti=0; ti<nt; ++ti){
    const int kt0 = k0 + (ti<<6);
    __syncthreads();                   // previous tile's reads complete
    {
      const float4* ksrc = (const float4*)(kh + (size_t)kt0*10);
      const float4* vsrc = (const float4*)(vh + (size_t)kt0*10);
      for (int i=t; i<320; i+=256){
        if (i < 160) ((float4*)kst)[i]     = ksrc[i];
        else         ((float4*)vst)[i-160] = vsrc[i-160];
      }
    }
    __syncthreads();                   // staging visible
    #pragma unroll 1
    for (int c8=0; c8<64; c8+=8){
      float s[8];
      #pragma unroll
      for (int u=0;u<8;u++){
        const float2* kp = (const float2*)(kst + (c8+u)*10);
        float sv = 0.f;
        #pragma unroll
        for (int i=0;i<5;i++){ float2 kk=kp[i]; sv=fmaf(qreg[2*i],kk.x,sv); sv=fmaf(qreg[2*i+1],kk.y,sv); }
        s[u]=sv;
      }
      float mc = s[0];
      #pragma unroll
      for (int u=1;u<8;u++) mc = fmaxf(mc, s[u]);
      const float mnew = fmaxf(m, mc);
      const float corr = fexp2(L2E*(m - mnew));   // m=-inf first chunk -> 0
      l *= corr;
      #pragma unroll
      for (int d=0;d<10;d++) acc[d]*=corr;
      #pragma unroll
      for (int u=0;u<8;u++){
        const float p = fexp2(L2E*(s[u]-mnew));
        l += p;
        const float2* vp = (const float2*)(vst + (c8+u)*10);
        #pragma unroll
        for (int i=0;i<5;i++){ float2 vv=vp[i]; acc[2*i]=fmaf(p,vv.x,acc[2*i]); acc[2*i+1]=fmaf(p,vv.y,acc[2*i+1]); }
      }
      m = mnew;
    }
  }
  float* pp = part + ((size_t)(head*Bsz + qr)*gridDim.z + ks)*12;
  pp[0]=m; pp[1]=l;
  #pragma unroll
  for (int d=0;d<10;d++) pp[2+d]=acc[d];
}

// ---------------------------------------------------------------------------
// Kernel 3 (R10 LDS-weights version, unchanged): merge + out_proj + LN +
// MLP(exact GELU) + LN + head. One wave per row.
// ---------------------------------------------------------------------------
extern "C" __global__ void __launch_bounds__(256)
tail_k(const float* __restrict__ part, int ns, const float* __restrict__ hn,
       const float* __restrict__ out_proj_w, const float* __restrict__ out_proj_b,
       const float* __restrict__ fc1_w, const float* __restrict__ fc1_b,
       const float* __restrict__ fc2_w, const float* __restrict__ fc2_b,
       const float* __restrict__ ln_g, const float* __restrict__ ln_b,
       const float* __restrict__ out_w, const float* __restrict__ out_b,
       float* __restrict__ out)
{
  __shared__ __align__(16) float buf[4][32];
  __shared__ float wl[2880];
  const int tidb = threadIdx.x;
  for (int i=tidb;i<900;i+=256) wl[i]       = out_proj_w[i];
  for (int i=tidb;i<900;i+=256) wl[900+i]   = fc1_w[i];
  for (int i=tidb;i<900;i+=256) wl[1800+i]  = fc2_w[i];
  if (tidb < 90) wl[2700+tidb] = out_w[tidb];
  const int wave = tidb >> 6;
  const int lane = tidb & 63;
  const int b = blockIdx.x*4 + wave;
  const bool act = (lane < NE);
  if (lane < 32) buf[wave][lane] = 0.f;
  __syncthreads();
  if (act) {
    const int head = lane/10, dd = lane%10;
    const float* p = part + ((size_t)(head*Bsz + b)*ns)*12;
    float M = -INFINITY, L = 0.f, O = 0.f;
    for (int i=0;i<ns;i++){
      const float mi = p[i*12], li = p[i*12+1], ai = p[i*12+2+dd];
      const float Mn = fmaxf(M, mi);
      const float cw = fexp2(L2E*(M - Mn));
      const float wi = fexp2(L2E*(mi - Mn));
      L = fmaf(li, wi, L*cw);
      O = fmaf(ai, wi, O*cw);
      M = Mn;
    }
    buf[wave][lane] = O / L;
  }
  __builtin_amdgcn_wave_barrier();
  float arr[32];
  loadarr32(arr, &buf[wave][0]);
  const float hv = act ? hn[b*NE+lane] : 0.f;
  float x = 0.f;
  if (act) {
    float a = out_proj_b[lane];
    #pragma unroll
    for (int k2=0;k2<NE;k2++) a = fmaf(wl[lane*NE+k2], arr[k2], a);
    x = a + hv;                       // attn_out + h_n
  }
  __builtin_amdgcn_wave_barrier();
  if (act) buf[wave][lane] = x;
  __builtin_amdgcn_wave_barrier();
  loadarr32(arr, &buf[wave][0]);
  float s1=0.f, s2=0.f;
  #pragma unroll
  for (int k2=0;k2<32;k2++){ s1+=arr[k2]; s2=fmaf(arr[k2],arr[k2],s2); }
  float mu = s1*(1.f/30.f);
  float var = s2*(1.f/30.f) - mu*mu;
  float rs = rsqrtf(var + 1e-5f);
  float x1 = 0.f;
  if (act) x1 = fmaf((x-mu)*rs, ln_g[lane], ln_b[lane]);
  __builtin_amdgcn_wave_barrier();
  if (act) buf[wave][lane] = x1;
  __builtin_amdgcn_wave_barrier();
  loadarr32(arr, &buf[wave][0]);
  float gv = 0.f;
  if (act) {
    float a = fc1_b[lane];
    #pragma unroll
    for (int k2=0;k2<NE;k2++) a = fmaf(wl[900+lane*NE+k2], arr[k2], a);
    gv = 0.5f*a*(1.f + erff(a*0.70710678118654752f));
  }
  __builtin_amdgcn_wave_barrier();
  if (act) buf[wave][lane] = gv;
  __builtin_amdgcn_wave_barrier();
  loadarr32(arr, &buf[wave][0]);
  float y = 0.f;
  if (act) {
    float a = fc2_b[lane];
    #pragma unroll
    for (int k2=0;k2<NE;k2++) a = fmaf(wl[1800+lane*NE+k2], arr[k2], a);
    y = x1 + a;                        // residual x1 + fc
  }
  __builtin_amdgcn_wave_barrier();
  if (act) buf[wave][lane] = y;
  __builtin_amdgcn_wave_barrier();
  loadarr32(arr, &buf[wave][0]);
  s1=0.f; s2=0.f;
  #pragma unroll
  for (int k2=0;k2<32;k2++){ s1+=arr[k2]; s2=fmaf(arr[k2],arr[k2],s2); }
  mu = s1*(1.f/30.f);
  var = s2*(1.f/30.f) - mu*mu;
  rs = rsqrtf(var + 1e-5f);
  float x2 = 0.f;
  if (act) x2 = fmaf((y-mu)*rs, ln_g[lane], ln_b[lane]);
  __builtin_amdgcn_wave_barrier();
  if (act) buf[wave][lane] = x2;
  __builtin_amdgcn_wave_barrier();
  loadarr32(arr, &buf[wave][0]);
  if (lane < 3) {
    float a = out_b[lane];
    #pragma unroll
    for (int k2=0;k2<NE;k2++) a = fmaf(wl[2700+lane*NE+k2], arr[k2], a);
    out[b*3 + lane] = a;
  }
}

extern "C" void kernel_launch(void* const* d_in, const int* in_sizes, int n_in,
                              void* d_out, int out_size, void* d_ws, size_t ws_size,
                              hipStream_t stream)
{
  const float* input      = (const float*)d_in[0];
  const float* w_ih       = (const float*)d_in[1];
  const float* w_hh       = (const float*)d_in[2];
  const float* b_ih       = (const float*)d_in[3];
  const float* b_hh       = (const float*)d_in[4];
  const float* in_proj_w  = (const float*)d_in[5];
  const float* in_proj_b  = (const float*)d_in[6];
  const float* out_proj_w = (const float*)d_in[7];
  const float* out_proj_b = (const float*)d_in[8];
  const float* fc1_w      = (const float*)d_in[9];
  const float* fc1_b      = (const float*)d_in[10];
  const float* fc2_w      = (const float*)d_in[11];
  const float* fc2_b      = (const float*)d_in[12];
  const float* ln_g       = (const float*)d_in[13];
  const float* ln_b       = (const float*)d_in[14];
  const float* out_w      = (const float*)d_in[15];
  const float* out_b      = (const float*)d_in[16];

  float* ws = (float*)d_ws;
  float* qo   = ws;                 // [3][4096][10]
  float* ko   = ws + 122880;        // [3][4096][10]
  float* vo   = ws + 245760;        // [3][4096][10]
  float* hn   = ws + 368640;        // [4096][30]
  float* part = ws + 491520;        // [3][4096][NS][12]

  const size_t need16 = ((size_t)491520 + (size_t)3*4096*16*12) * 4;
  const int NS = (ws_size >= need16) ? 16 : 8;

  lstm_k<<<Bsz/16, 64, 0, stream>>>(input, w_ih, w_hh, b_ih, b_hh,
                                    in_proj_w, in_proj_b, qo, ko, vo, hn);
  attn_part<<<dim3(Bsz/256, 3, NS), 256, 0, stream>>>(qo, ko, vo, part, Bsz/NS);
  tail_k<<<Bsz/4, 256, 0, stream>>>(part, NS, hn, out_proj_w, out_proj_b,
                                    fc1_w, fc1_b, fc2_w, fc2_b,
                                    ln_g, ln_b, out_w, out_b, (float*)d_out);
}